// Round 10
// baseline (144.767 us; speedup 1.0000x reference)
//
#include <hip/hip_runtime.h>
#include <hip/hip_fp16.h>

#define HH 128
#define NB 4
#define NVOX (NB * HH * HH * HH)   // 8,388,608 = 2^23 voxels per image

// pass1 v4: lane holds d = {2*lane, 2*lane+1} (float2); each wave computes TWO
// adjacent w-columns (shared halo: 4 loads/4 cstages per row for 2 outputs,
// two independent dep-streams for latency hiding). Block = 4 waves = 8 cols.
#define NBLK1 1024                 // img2 * b4 * hstrip8 * wgroup16
#define GRID2 512
#define TPB 256

// Slot arrays: every slot written by pass1 every call before pass2 reads them
// (dispatch-boundary ordering). No init kernel, no atomics on these.
__device__ __align__(16) unsigned int g_bmin[NBLK1];
__device__ __align__(16) unsigned int g_bmax[NBLK1];

union U4H8 { uint4 u; __half2 h[4]; };

// ---------------------------------------------------------------------------
// Pass 1 v4: separable Sobel magnitude, register/shfl, no LDS.
// Ops per axis: s=(1,2,1), d=(-1,0,1), u=(1,1,1).
//   Sx=Gssd Sy=Gsds Sz=Gdss ; Sd11=Gsud-Gsdu Sd12=Gsud+Gsdu
//   Sd21=Gdus-Guds Sd22=Gdus+Guds ; Sd31=Gusd-Gdsu Sd32=Gusd+Gdsu
// Reflect pad=1: -1 -> 1, 128 -> 126. d-neighbors via 2 shuffles + edge selects.
// ---------------------------------------------------------------------------
__global__ __launch_bounds__(256) void pass1_kernel(
    const float* __restrict__ x, const float* __restrict__ y,
    __half* __restrict__ magx, __half* __restrict__ magy,
    float* __restrict__ out) {
    int bid = blockIdx.x;
    int tid = threadIdx.x;
    if (bid == 0 && tid == 0) out[0] = 0.0f;   // poison-clear for pass2 atomics

    int lane = tid & 63, wid = tid >> 6;
    int wg  = bid & 15;
    int hs  = (bid >> 4) & 7;
    int b   = (bid >> 7) & 3;
    int img = bid >> 9;

    const float* __restrict__ src = img ? y : x;
    __half* __restrict__ dst = img ? magy : magx;

    int w0 = wg * 8 + wid * 2;         // first output column (even)
    int w1 = w0 + 1;                   // second output column
    // halo columns (reflect): cw[0]=w0-1, cw[1]=w0, cw[2]=w1, cw[3]=w1+1
    int cw0 = (w0 == 0) ? 1 : (w0 - 1);
    int cw3 = (w1 == 127) ? 126 : (w1 + 1);
    int h0 = hs << 4;
    const float2* base2 = (const float2*)(src + ((size_t)b << 21));

    // ring state per output column: 7 float2 quantities x 3 slots
    float2 sbD[2][3], ubD[2][3], dbS[2][3], sbS[2][3], ubS[2][3], dbU[2][3], sbU[2][3];
    float mn = 3.4e38f, mx = 0.0f;
    bool l0 = (lane == 0), l63 = (lane == 63);

    // c-stage along d: S/D/U for both packed components; 2 shuffles + 2 selects.
    auto cstage = [&](float2 q, float2& S, float2& D, float2& U) {
        float Lxs = __shfl_up(q.y, 1);
        float Rys = __shfl_down(q.x, 1);
        float Lx = l0  ? q.y : Lxs;    // d=2i-1 (reflect at d=0 -> q[1])
        float Ry = l63 ? q.x : Rys;    // d=2i+2 (reflect at d=127 -> q[126])
        float tx = Lx + q.y;
        float ty = q.x + Ry;
        S.x = fmaf(2.0f, q.x, tx);
        S.y = fmaf(2.0f, q.y, ty);
        D.x = q.y - Lx;
        D.y = Ry - q.x;
        U.x = tx + q.x;
        U.y = ty + q.y;
    };

#pragma unroll
    for (int r = 0; r < 18; ++r) {
        int hr = h0 + r - 1;
        hr = (hr < 0) ? 1 : ((hr > 127) ? 126 : hr);
        int rowb = (hr << 7);
        float2 q0 = base2[(size_t)((rowb + cw0) << 6) + lane];
        float2 q1 = base2[(size_t)((rowb + w0)  << 6) + lane];
        float2 q2 = base2[(size_t)((rowb + w1)  << 6) + lane];
        float2 q3 = base2[(size_t)((rowb + cw3) << 6) + lane];

        float2 S[4], D[4], U[4];
        cstage(q0, S[0], D[0], U[0]);
        cstage(q1, S[1], D[1], U[1]);
        cstage(q2, S[2], D[2], U[2]);
        cstage(q3, S[3], D[3], U[3]);

        int slot = r % 3;
#pragma unroll
        for (int o = 0; o < 2; ++o) {
            float2 D0 = D[o], D1 = D[o + 1], D2 = D[o + 2];
            float2 S0 = S[o], S1 = S[o + 1], S2 = S[o + 2];
            float2 U0 = U[o], U1 = U[o + 1], U2 = U[o + 2];
            float2 tD = { D0.x + D2.x, D0.y + D2.y };
            sbD[o][slot] = { fmaf(2.0f, D1.x, tD.x), fmaf(2.0f, D1.y, tD.y) };
            ubD[o][slot] = { tD.x + D1.x, tD.y + D1.y };
            float2 tS = { S0.x + S2.x, S0.y + S2.y };
            sbS[o][slot] = { fmaf(2.0f, S1.x, tS.x), fmaf(2.0f, S1.y, tS.y) };
            ubS[o][slot] = { tS.x + S1.x, tS.y + S1.y };
            dbS[o][slot] = { S2.x - S0.x, S2.y - S0.y };
            float2 tU = { U0.x + U2.x, U0.y + U2.y };
            sbU[o][slot] = { fmaf(2.0f, U1.x, tU.x), fmaf(2.0f, U1.y, tU.y) };
            dbU[o][slot] = { U2.x - U0.x, U2.y - U0.y };
        }

        if (r >= 2) {
            int s0 = (r - 2) % 3, s1 = (r - 1) % 3, s2 = slot;
            int hout = h0 + r - 2;
#pragma unroll
            for (int o = 0; o < 2; ++o) {
                float2 m2;
#pragma unroll
                for (int c = 0; c < 2; ++c) {
                    float vsbD0 = c ? sbD[o][s0].y : sbD[o][s0].x;
                    float vsbD1 = c ? sbD[o][s1].y : sbD[o][s1].x;
                    float vsbD2 = c ? sbD[o][s2].y : sbD[o][s2].x;
                    float vubD0 = c ? ubD[o][s0].y : ubD[o][s0].x;
                    float vubD1 = c ? ubD[o][s1].y : ubD[o][s1].x;
                    float vubD2 = c ? ubD[o][s2].y : ubD[o][s2].x;
                    float vdbS0 = c ? dbS[o][s0].y : dbS[o][s0].x;
                    float vdbS1 = c ? dbS[o][s1].y : dbS[o][s1].x;
                    float vdbS2 = c ? dbS[o][s2].y : dbS[o][s2].x;
                    float vsbS0 = c ? sbS[o][s0].y : sbS[o][s0].x;
                    float vsbS2 = c ? sbS[o][s2].y : sbS[o][s2].x;
                    float vubS0 = c ? ubS[o][s0].y : ubS[o][s0].x;
                    float vubS2 = c ? ubS[o][s2].y : ubS[o][s2].x;
                    float vdbU0 = c ? dbU[o][s0].y : dbU[o][s0].x;
                    float vdbU1 = c ? dbU[o][s1].y : dbU[o][s1].x;
                    float vdbU2 = c ? dbU[o][s2].y : dbU[o][s2].x;
                    float vsbU0 = c ? sbU[o][s0].y : sbU[o][s0].x;
                    float vsbU2 = c ? sbU[o][s2].y : sbU[o][s2].x;

                    float tsbD = vsbD0 + vsbD2;
                    float Gssd = fmaf(2.0f, vsbD1, tsbD);
                    float Gusd = tsbD + vsbD1;
                    float tubD = vubD0 + vubD2;
                    float Gsud = fmaf(2.0f, vubD1, tubD);
                    float tdbS = vdbS0 + vdbS2;
                    float Gsds = fmaf(2.0f, vdbS1, tdbS);
                    float Guds = tdbS + vdbS1;
                    float Gdss = vsbS2 - vsbS0;
                    float Gdus = vubS2 - vubS0;
                    float tdbU = vdbU0 + vdbU2;
                    float Gsdu = fmaf(2.0f, vdbU1, tdbU);
                    float Gdsu = vsbU2 - vsbU0;

                    float f0 = Gssd;
                    float f1 = Gsds;
                    float f2 = Gdss;
                    float f3 = Gsud - Gsdu;
                    float f4 = Gsud + Gsdu;
                    float f5 = Gdus - Guds;
                    float f6 = Gdus + Guds;
                    float f7 = Gusd - Gdsu;
                    float f8 = Gusd + Gdsu;

                    const float e1 = 1e-6f;
                    float s = 9.0f * 1e-6f;
                    float u;
                    u = f0 + e1; s = fmaf(u, u, s);
                    u = f1 + e1; s = fmaf(u, u, s);
                    u = f2 + e1; s = fmaf(u, u, s);
                    u = f3 + e1; s = fmaf(u, u, s);
                    u = f4 + e1; s = fmaf(u, u, s);
                    u = f5 + e1; s = fmaf(u, u, s);
                    u = f6 + e1; s = fmaf(u, u, s);
                    u = f7 + e1; s = fmaf(u, u, s);
                    u = f8 + e1; s = fmaf(u, u, s);
                    float m = sqrtf(s);
                    if (c) m2.y = m; else m2.x = m;
                }

                __half2 hm2 = __float22half2_rn(m2);
                float2 mr = __half22float2(hm2);
                int h2idx = (((b * 128 + hout) * 128 + (w0 + o)) << 6) + lane;
                __builtin_nontemporal_store(*(unsigned int*)&hm2,
                    (unsigned int*)((__half2*)dst + h2idx));
                mn = fminf(mn, fminf(mr.x, mr.y));
                mx = fmaxf(mx, fmaxf(mr.x, mr.y));
            }
        }
    }

    // Block min/max reduce (uint trick valid: m > 0), plain store to unique slot
    unsigned int umn = __float_as_uint(mn);
    unsigned int umx = __float_as_uint(mx);
#pragma unroll
    for (int off = 32; off > 0; off >>= 1) {
        unsigned int a1 = __shfl_down(umn, off, 64);
        unsigned int b1 = __shfl_down(umx, off, 64);
        umn = (a1 < umn) ? a1 : umn;
        umx = (b1 > umx) ? b1 : umx;
    }
    __shared__ unsigned int smn[4], smx[4];
    if (lane == 0) { smn[wid] = umn; smx[wid] = umx; }
    __syncthreads();
    if (tid == 0) {
        unsigned int m0 = smn[0] < smn[1] ? smn[0] : smn[1];
        unsigned int m1 = smn[2] < smn[3] ? smn[2] : smn[3];
        unsigned int x0 = smx[0] > smx[1] ? smx[0] : smx[1];
        unsigned int x1 = smx[2] > smx[3] ? smx[2] : smx[3];
        g_bmin[bid] = (m0 < m1 ? m0 : m1);
        g_bmax[bid] = (x0 > x1 ? x0 : x1);
    }
}

// ---------------------------------------------------------------------------
// Pass 2 (R7-proven structure; slots now 1024): every block redundantly
// reduces the 8 KB of min/max slots (LLC-resident; no fences), streams its
// sequential shard of both fp16 mag arrays, one pre-scaled atomicAdd(out).
// ---------------------------------------------------------------------------
__global__ __launch_bounds__(TPB) void pass2_kernel(
    const uint4* __restrict__ magx8, const uint4* __restrict__ magy8,
    float* __restrict__ out) {
    int tid = threadIdx.x, bid = blockIdx.x;
    int lane = tid & 63, wid = tid >> 6;
    __shared__ unsigned int sred[4][4];
    __shared__ float smm[4];
    __shared__ float sv[4];

    // ---- redundant global min/max reduce: 512 slots per image = 128 uint4 ----
    const uint4* bmin4 = (const uint4*)g_bmin;   // [0,128): img x, [128,256): img y
    const uint4* bmax4 = (const uint4*)g_bmax;
    unsigned int v0 = 0xFFFFFFFFu, v1 = 0u, v2 = 0xFFFFFFFFu, v3 = 0u;
    if (tid < 128) {
        uint4 a = bmin4[tid];
        uint4 b = bmax4[tid];
        uint4 c = bmin4[tid + 128];
        uint4 d = bmax4[tid + 128];
        unsigned int a01 = (a.x < a.y) ? a.x : a.y, a23 = (a.z < a.w) ? a.z : a.w;
        unsigned int b01 = (b.x > b.y) ? b.x : b.y, b23 = (b.z > b.w) ? b.z : b.w;
        unsigned int c01 = (c.x < c.y) ? c.x : c.y, c23 = (c.z < c.w) ? c.z : c.w;
        unsigned int d01 = (d.x > d.y) ? d.x : d.y, d23 = (d.z > d.w) ? d.z : d.w;
        v0 = (a01 < a23) ? a01 : a23;
        v1 = (b01 > b23) ? b01 : b23;
        v2 = (c01 < c23) ? c01 : c23;
        v3 = (d01 > d23) ? d01 : d23;
    }
#pragma unroll
    for (int off = 32; off > 0; off >>= 1) {
        unsigned int t0 = __shfl_down(v0, off, 64);
        unsigned int t1 = __shfl_down(v1, off, 64);
        unsigned int t2 = __shfl_down(v2, off, 64);
        unsigned int t3 = __shfl_down(v3, off, 64);
        v0 = (t0 < v0) ? t0 : v0;
        v1 = (t1 > v1) ? t1 : v1;
        v2 = (t2 < v2) ? t2 : v2;
        v3 = (t3 > v3) ? t3 : v3;
    }
    if (lane == 0) { sred[wid][0] = v0; sred[wid][1] = v1; sred[wid][2] = v2; sred[wid][3] = v3; }
    __syncthreads();
    if (tid == 0) {
        unsigned int r0 = sred[0][0], r1 = sred[0][1], r2 = sred[0][2], r3 = sred[0][3];
#pragma unroll
        for (int w = 1; w < 4; ++w) {
            r0 = (sred[w][0] < r0) ? sred[w][0] : r0;
            r1 = (sred[w][1] > r1) ? sred[w][1] : r1;
            r2 = (sred[w][2] < r2) ? sred[w][2] : r2;
            r3 = (sred[w][3] > r3) ? sred[w][3] : r3;
        }
        smm[0] = __uint_as_float(r0);
        smm[1] = __uint_as_float(r1);
        smm[2] = __uint_as_float(r2);
        smm[3] = __uint_as_float(r3);
    }
    __syncthreads();

    // ---- normalize + L1 partial sum over this block's sequential shard ----
    float mnx = smm[0], mxx = smm[1], mny = smm[2], mxy = smm[3];
    float ix = 1.0f / (mxx - mnx + 1e-6f);
    float iy = 1.0f / (mxy - mny + 1e-6f);
    float cx = -mnx * ix;
    float cy = -mny * iy;

    float s = 0.0f;
    // NVOX/8 = 1,048,576 uint4 per array; per block 2048 sequential uint4
#pragma unroll
    for (int k = 0; k < 8; ++k) {
        int i = bid * 2048 + k * TPB + tid;
        U4H8 qa, qb;
        qa.u = magx8[i];
        qb.u = magy8[i];
#pragma unroll
        for (int j = 0; j < 4; ++j) {
            float2 va = __half22float2(qa.h[j]);
            float2 vb = __half22float2(qb.h[j]);
            s += fabsf(fmaf(va.x, ix, cx) - fmaf(vb.x, iy, cy));
            s += fabsf(fmaf(va.y, ix, cx) - fmaf(vb.y, iy, cy));
        }
    }
#pragma unroll
    for (int off = 32; off > 0; off >>= 1) s += __shfl_down(s, off, 64);
    if (lane == 0) sv[wid] = s;
    __syncthreads();
    if (tid == 0) {
        float partial = ((sv[0] + sv[1]) + (sv[2] + sv[3])) * (1.0f / (float)NVOX); // *2^-23 exact
        if (bid == 0) partial += 1e-6f;
        atomicAdd(out, partial);
    }
}

extern "C" void kernel_launch(void* const* d_in, const int* in_sizes, int n_in,
                              void* d_out, int out_size, void* d_ws, size_t ws_size,
                              hipStream_t stream) {
    const float* x = (const float*)d_in[0];
    const float* y = (const float*)d_in[1];
    // d_in[2] = kernels (weights hardcoded via separable factorization)
    float* out = (float*)d_out;

    __half* magx = (__half*)d_ws;            // NVOX halfs (16 MiB)
    __half* magy = magx + NVOX;              // NVOX halfs (16 MiB)

    pass1_kernel<<<NBLK1, 256, 0, stream>>>(x, y, magx, magy, out);
    pass2_kernel<<<GRID2, TPB, 0, stream>>>((const uint4*)magx, (const uint4*)magy, out);
}

// Round 11
// 141.036 us; speedup vs baseline: 1.0265x; 1.0265x over previous
//
#include <hip/hip_runtime.h>
#include <hip/hip_fp16.h>

#define HH 128
#define NB 4
#define NVOX (NB * HH * HH * HH)   // 8,388,608 = 2^23 voxels per image

// pass1 v5: lane holds d = {2*lane, 2*lane+1}; one wave = one w-column,
// 18-row slide (R9 structure). All arithmetic on 2-wide float vectors so the
// backend can emit packed VOP3P (v_pk_fma_f32 / v_pk_add_f32) — ~40% fewer
// VALU instructions at unchanged register/occupancy cost.
#define NBLK1 2048                 // img2 * b4 * hstrip8 * wgroup32
#define GRID2 512
#define TPB 256

typedef float vf2 __attribute__((ext_vector_type(2)));

// Slot arrays: every slot written by pass1 every call before pass2 reads them
// (dispatch-boundary ordering). No init kernel, no atomics on these.
__device__ __align__(16) unsigned int g_bmin[NBLK1];
__device__ __align__(16) unsigned int g_bmax[NBLK1];

union U4H8 { uint4 u; __half2 h[4]; };

// ---------------------------------------------------------------------------
// Pass 1 v5 (register/shfl, packed-fp32 math, no LDS): separable Sobel mag.
// Ops per axis: s=(1,2,1), d=(-1,0,1), u=(1,1,1).
//   Sx=Gssd Sy=Gsds Sz=Gdss ; Sd11=Gsud-Gsdu Sd12=Gsud+Gsdu
//   Sd21=Gdus-Guds Sd22=Gdus+Guds ; Sd31=Gusd-Gdsu Sd32=Gusd+Gdsu
// Reflect pad=1: -1 -> 1, 128 -> 126. h,w wave-uniform; d via lane-selects:
//   LV=(q[2i-1],q[2i]) via shfl_up of .y; RV=(q[2i+1],q[2i+2]) via shfl_down
//   of .x; reflect at d=0 -> q[1], d=127 -> q[126].
// ---------------------------------------------------------------------------
__global__ __launch_bounds__(256) void pass1_kernel(
    const float* __restrict__ x, const float* __restrict__ y,
    __half* __restrict__ magx, __half* __restrict__ magy,
    float* __restrict__ out) {
    int bid = blockIdx.x;
    int tid = threadIdx.x;
    if (bid == 0 && tid == 0) out[0] = 0.0f;   // poison-clear for pass2 atomics

    int lane = tid & 63, wid = tid >> 6;
    int wg  = bid & 31;
    int hs  = (bid >> 5) & 7;
    int b   = (bid >> 8) & 3;
    int img = bid >> 10;

    const float* __restrict__ src = img ? y : x;
    __half* __restrict__ dst = img ? magy : magx;

    int w  = wg * 4 + wid;
    int wm = (w == 0) ? 1 : (w - 1);
    int wp = (w == 127) ? 126 : (w + 1);
    int h0 = hs << 4;
    const vf2* base2 = (const vf2*)(src + ((size_t)b << 21));

    const vf2 two = {2.0f, 2.0f};
    const vf2 e1v = {1e-6f, 1e-6f};

    // ring state: vf2 per slot (components = two d positions)
    vf2 sbD[3], ubD[3], dbS[3], sbS[3], ubS[3], dbU[3], sbU[3];
    float mn = 3.4e38f, mx = 0.0f;
    bool l0 = (lane == 0), l63 = (lane == 63);

    // c-stage along d: S/D/U packed; 2 shuffles + 2 selects + 4 pk-ops.
    auto cstage = [&](vf2 q, vf2& S, vf2& D, vf2& U) {
        float Lxs = __shfl_up(q.y, 1);
        float Rys = __shfl_down(q.x, 1);
        float Lx = l0  ? q.y : Lxs;    // d=2i-1 (reflect at d=0 -> q[1])
        float Ry = l63 ? q.x : Rys;    // d=2i+2 (reflect at d=127 -> q[126])
        vf2 LV = {Lx, q.x};
        vf2 RV = {q.y, Ry};
        vf2 t = LV + RV;
        S = __builtin_elementwise_fma(two, q, t);
        D = RV - LV;
        U = t + q;
    };

#pragma unroll
    for (int r = 0; r < 18; ++r) {
        int hr = h0 + r - 1;
        hr = (hr < 0) ? 1 : ((hr > 127) ? 126 : hr);
        const vf2* rm = base2 + (((hr << 7) + wm) << 6);
        const vf2* rc = base2 + (((hr << 7) + w)  << 6);
        const vf2* rp = base2 + (((hr << 7) + wp) << 6);
        vf2 qm = rm[lane], qc = rc[lane], qp = rp[lane];

        vf2 S0, D0, U0, S1, D1, U1, S2, D2, U2;
        cstage(qm, S0, D0, U0);
        cstage(qc, S1, D1, U1);
        cstage(qp, S2, D2, U2);

        int slot = r % 3;
        vf2 tD = D0 + D2;
        sbD[slot] = __builtin_elementwise_fma(two, D1, tD);
        ubD[slot] = tD + D1;
        vf2 tS = S0 + S2;
        sbS[slot] = __builtin_elementwise_fma(two, S1, tS);
        ubS[slot] = tS + S1;
        dbS[slot] = S2 - S0;
        vf2 tU = U0 + U2;
        sbU[slot] = __builtin_elementwise_fma(two, U1, tU);
        dbU[slot] = U2 - U0;

        if (r >= 2) {
            int s0 = (r - 2) % 3, s1 = (r - 1) % 3, s2 = slot;

            vf2 tsbD = sbD[s0] + sbD[s2];
            vf2 Gssd = __builtin_elementwise_fma(two, sbD[s1], tsbD);
            vf2 Gusd = tsbD + sbD[s1];
            vf2 tubD = ubD[s0] + ubD[s2];
            vf2 Gsud = __builtin_elementwise_fma(two, ubD[s1], tubD);
            vf2 tdbS = dbS[s0] + dbS[s2];
            vf2 Gsds = __builtin_elementwise_fma(two, dbS[s1], tdbS);
            vf2 Guds = tdbS + dbS[s1];
            vf2 Gdss = sbS[s2] - sbS[s0];
            vf2 Gdus = ubS[s2] - ubS[s0];
            vf2 tdbU = dbU[s0] + dbU[s2];
            vf2 Gsdu = __builtin_elementwise_fma(two, dbU[s1], tdbU);
            vf2 Gdsu = sbU[s2] - sbU[s0];

            vf2 f0 = Gssd;
            vf2 f1 = Gsds;
            vf2 f2 = Gdss;
            vf2 f3 = Gsud - Gsdu;
            vf2 f4 = Gsud + Gsdu;
            vf2 f5 = Gdus - Guds;
            vf2 f6 = Gdus + Guds;
            vf2 f7 = Gusd - Gdsu;
            vf2 f8 = Gusd + Gdsu;

            vf2 s = {9.0f * 1e-6f, 9.0f * 1e-6f};
            vf2 u;
            u = f0 + e1v; s = __builtin_elementwise_fma(u, u, s);
            u = f1 + e1v; s = __builtin_elementwise_fma(u, u, s);
            u = f2 + e1v; s = __builtin_elementwise_fma(u, u, s);
            u = f3 + e1v; s = __builtin_elementwise_fma(u, u, s);
            u = f4 + e1v; s = __builtin_elementwise_fma(u, u, s);
            u = f5 + e1v; s = __builtin_elementwise_fma(u, u, s);
            u = f6 + e1v; s = __builtin_elementwise_fma(u, u, s);
            u = f7 + e1v; s = __builtin_elementwise_fma(u, u, s);
            u = f8 + e1v; s = __builtin_elementwise_fma(u, u, s);

            float2 m2;
            m2.x = sqrtf(s.x);
            m2.y = sqrtf(s.y);

            __half2 hm2 = __float22half2_rn(m2);
            float2 mr = __half22float2(hm2);
            int hout = h0 + r - 2;
            int h2idx = (((b * 128 + hout) * 128 + w) << 6) + lane;
            __builtin_nontemporal_store(*(unsigned int*)&hm2,
                (unsigned int*)((__half2*)dst + h2idx));
            mn = fminf(mn, fminf(mr.x, mr.y));
            mx = fmaxf(mx, fmaxf(mr.x, mr.y));
        }
    }

    // Block min/max reduce (uint trick valid: m > 0), plain store to unique slot
    unsigned int umn = __float_as_uint(mn);
    unsigned int umx = __float_as_uint(mx);
#pragma unroll
    for (int off = 32; off > 0; off >>= 1) {
        unsigned int a1 = __shfl_down(umn, off, 64);
        unsigned int b1 = __shfl_down(umx, off, 64);
        umn = (a1 < umn) ? a1 : umn;
        umx = (b1 > umx) ? b1 : umx;
    }
    __shared__ unsigned int smn[4], smx[4];
    if (lane == 0) { smn[wid] = umn; smx[wid] = umx; }
    __syncthreads();
    if (tid == 0) {
        unsigned int m0 = smn[0] < smn[1] ? smn[0] : smn[1];
        unsigned int m1 = smn[2] < smn[3] ? smn[2] : smn[3];
        unsigned int x0 = smx[0] > smx[1] ? smx[0] : smx[1];
        unsigned int x1 = smx[2] > smx[3] ? smx[2] : smx[3];
        g_bmin[bid] = (m0 < m1 ? m0 : m1);
        g_bmax[bid] = (x0 > x1 ? x0 : x1);
    }
}

// ---------------------------------------------------------------------------
// Pass 2 (R9-proven, slots = 2048): every block redundantly reduces the 16 KB
// of min/max slots (LLC-resident; no fences), streams its sequential shard of
// both fp16 mag arrays, one pre-scaled atomicAdd(out).
// ---------------------------------------------------------------------------
__global__ __launch_bounds__(TPB) void pass2_kernel(
    const uint4* __restrict__ magx8, const uint4* __restrict__ magy8,
    float* __restrict__ out) {
    int tid = threadIdx.x, bid = blockIdx.x;
    int lane = tid & 63, wid = tid >> 6;
    __shared__ unsigned int sred[4][4];
    __shared__ float smm[4];
    __shared__ float sv[4];

    // ---- redundant global min/max reduce: 1024 slots per image = 256 uint4 ----
    const uint4* bmin4 = (const uint4*)g_bmin;   // [0,256): img x, [256,512): img y
    const uint4* bmax4 = (const uint4*)g_bmax;
    uint4 a = bmin4[tid];
    uint4 b = bmax4[tid];
    uint4 c = bmin4[tid + 256];
    uint4 d = bmax4[tid + 256];
    unsigned int a01 = (a.x < a.y) ? a.x : a.y, a23 = (a.z < a.w) ? a.z : a.w;
    unsigned int b01 = (b.x > b.y) ? b.x : b.y, b23 = (b.z > b.w) ? b.z : b.w;
    unsigned int c01 = (c.x < c.y) ? c.x : c.y, c23 = (c.z < c.w) ? c.z : c.w;
    unsigned int d01 = (d.x > d.y) ? d.x : d.y, d23 = (d.z > d.w) ? d.z : d.w;
    unsigned int v0 = (a01 < a23) ? a01 : a23;
    unsigned int v1 = (b01 > b23) ? b01 : b23;
    unsigned int v2 = (c01 < c23) ? c01 : c23;
    unsigned int v3 = (d01 > d23) ? d01 : d23;
#pragma unroll
    for (int off = 32; off > 0; off >>= 1) {
        unsigned int t0 = __shfl_down(v0, off, 64);
        unsigned int t1 = __shfl_down(v1, off, 64);
        unsigned int t2 = __shfl_down(v2, off, 64);
        unsigned int t3 = __shfl_down(v3, off, 64);
        v0 = (t0 < v0) ? t0 : v0;
        v1 = (t1 > v1) ? t1 : v1;
        v2 = (t2 < v2) ? t2 : v2;
        v3 = (t3 > v3) ? t3 : v3;
    }
    if (lane == 0) { sred[wid][0] = v0; sred[wid][1] = v1; sred[wid][2] = v2; sred[wid][3] = v3; }
    __syncthreads();
    if (tid == 0) {
        unsigned int r0 = sred[0][0], r1 = sred[0][1], r2 = sred[0][2], r3 = sred[0][3];
#pragma unroll
        for (int w = 1; w < 4; ++w) {
            r0 = (sred[w][0] < r0) ? sred[w][0] : r0;
            r1 = (sred[w][1] > r1) ? sred[w][1] : r1;
            r2 = (sred[w][2] < r2) ? sred[w][2] : r2;
            r3 = (sred[w][3] > r3) ? sred[w][3] : r3;
        }
        smm[0] = __uint_as_float(r0);
        smm[1] = __uint_as_float(r1);
        smm[2] = __uint_as_float(r2);
        smm[3] = __uint_as_float(r3);
    }
    __syncthreads();

    // ---- normalize + L1 partial sum over this block's sequential shard ----
    float mnx = smm[0], mxx = smm[1], mny = smm[2], mxy = smm[3];
    float ix = 1.0f / (mxx - mnx + 1e-6f);
    float iy = 1.0f / (mxy - mny + 1e-6f);
    float cx = -mnx * ix;
    float cy = -mny * iy;

    float s = 0.0f;
    // NVOX/8 = 1,048,576 uint4 per array; per block 2048 sequential uint4
#pragma unroll
    for (int k = 0; k < 8; ++k) {
        int i = bid * 2048 + k * TPB + tid;
        U4H8 qa, qb;
        qa.u = magx8[i];
        qb.u = magy8[i];
#pragma unroll
        for (int j = 0; j < 4; ++j) {
            float2 va = __half22float2(qa.h[j]);
            float2 vb = __half22float2(qb.h[j]);
            s += fabsf(fmaf(va.x, ix, cx) - fmaf(vb.x, iy, cy));
            s += fabsf(fmaf(va.y, ix, cx) - fmaf(vb.y, iy, cy));
        }
    }
#pragma unroll
    for (int off = 32; off > 0; off >>= 1) s += __shfl_down(s, off, 64);
    if (lane == 0) sv[wid] = s;
    __syncthreads();
    if (tid == 0) {
        float partial = ((sv[0] + sv[1]) + (sv[2] + sv[3])) * (1.0f / (float)NVOX); // *2^-23 exact
        if (bid == 0) partial += 1e-6f;
        atomicAdd(out, partial);
    }
}

extern "C" void kernel_launch(void* const* d_in, const int* in_sizes, int n_in,
                              void* d_out, int out_size, void* d_ws, size_t ws_size,
                              hipStream_t stream) {
    const float* x = (const float*)d_in[0];
    const float* y = (const float*)d_in[1];
    // d_in[2] = kernels (weights hardcoded via separable factorization)
    float* out = (float*)d_out;

    __half* magx = (__half*)d_ws;            // NVOX halfs (16 MiB)
    __half* magy = magx + NVOX;              // NVOX halfs (16 MiB)

    pass1_kernel<<<NBLK1, 256, 0, stream>>>(x, y, magx, magy, out);
    pass2_kernel<<<GRID2, TPB, 0, stream>>>((const uint4*)magx, (const uint4*)magy, out);
}

// Round 12
// 131.488 us; speedup vs baseline: 1.1010x; 1.0726x over previous
//
#include <hip/hip_runtime.h>
#include <hip/hip_fp16.h>

#define HH 128
#define NB 4
#define NVOX (NB * HH * HH * HH)   // 8,388,608 = 2^23 voxels per image

// pass1 v6: v5's packed-fp32 math + v4's two-columns-per-wave halo sharing.
// lane holds d = {2*lane, 2*lane+1}; wave computes 2 adjacent w-columns
// (4 column loads + 4 cstages per row serve 2 outputs; two independent
// dep-streams). Block = 4 waves = 8 columns.
#define NBLK1 1024                 // img2 * b4 * hstrip8 * wgroup16
#define GRID2 512
#define TPB 256

typedef float vf2 __attribute__((ext_vector_type(2)));

// Slot arrays: every slot written by pass1 every call before pass2 reads them
// (dispatch-boundary ordering). No init kernel, no atomics on these.
__device__ __align__(16) unsigned int g_bmin[NBLK1];
__device__ __align__(16) unsigned int g_bmax[NBLK1];

union U4H8 { uint4 u; __half2 h[4]; };

// ---------------------------------------------------------------------------
// Pass 1 v6 (register/shfl, packed fp32, 2 cols/wave, no LDS).
// Ops per axis: s=(1,2,1), d=(-1,0,1), u=(1,1,1).
//   Sx=Gssd Sy=Gsds Sz=Gdss ; Sd11=Gsud-Gsdu Sd12=Gsud+Gsdu
//   Sd21=Gdus-Guds Sd22=Gdus+Guds ; Sd31=Gusd-Gdsu Sd32=Gusd+Gdsu
// Reflect pad=1: -1 -> 1, 128 -> 126. h,w wave-uniform; d via lane-selects.
// ---------------------------------------------------------------------------
__global__ __launch_bounds__(256) void pass1_kernel(
    const float* __restrict__ x, const float* __restrict__ y,
    __half* __restrict__ magx, __half* __restrict__ magy,
    float* __restrict__ out) {
    int bid = blockIdx.x;
    int tid = threadIdx.x;
    if (bid == 0 && tid == 0) out[0] = 0.0f;   // poison-clear for pass2 atomics

    int lane = tid & 63, wid = tid >> 6;
    int wg  = bid & 15;
    int hs  = (bid >> 4) & 7;
    int b   = (bid >> 7) & 3;
    int img = bid >> 9;

    const float* __restrict__ src = img ? y : x;
    __half* __restrict__ dst = img ? magy : magx;

    int w0 = wg * 8 + wid * 2;         // first output column (even, >0)
    int w1 = w0 + 1;                   // second output column
    int cw0 = (w0 == 0) ? 1 : (w0 - 1);
    int cw3 = (w1 == 127) ? 126 : (w1 + 1);
    int h0 = hs << 4;
    const vf2* base2 = (const vf2*)(src + ((size_t)b << 21));

    const vf2 two = {2.0f, 2.0f};
    const vf2 e1v = {1e-6f, 1e-6f};

    // ring state per output column: 7 vf2 quantities x 3 slots
    vf2 sbD[2][3], ubD[2][3], dbS[2][3], sbS[2][3], ubS[2][3], dbU[2][3], sbU[2][3];
    float mn = 3.4e38f, mx = 0.0f;
    bool l0 = (lane == 0), l63 = (lane == 63);

    // c-stage along d: S/D/U packed; 2 shuffles + 2 selects + 4 pk-ops.
    auto cstage = [&](vf2 q, vf2& S, vf2& D, vf2& U) {
        float Lxs = __shfl_up(q.y, 1);
        float Rys = __shfl_down(q.x, 1);
        float Lx = l0  ? q.y : Lxs;    // d=2i-1 (reflect at d=0 -> q[1])
        float Ry = l63 ? q.x : Rys;    // d=2i+2 (reflect at d=127 -> q[126])
        vf2 LV = {Lx, q.x};
        vf2 RV = {q.y, Ry};
        vf2 t = LV + RV;
        S = __builtin_elementwise_fma(two, q, t);
        D = RV - LV;
        U = t + q;
    };

#pragma unroll
    for (int r = 0; r < 18; ++r) {
        int hr = h0 + r - 1;
        hr = (hr < 0) ? 1 : ((hr > 127) ? 126 : hr);
        int rowb = (hr << 7);
        vf2 q0 = base2[(size_t)((rowb + cw0) << 6) + lane];
        vf2 q1 = base2[(size_t)((rowb + w0)  << 6) + lane];
        vf2 q2 = base2[(size_t)((rowb + w1)  << 6) + lane];
        vf2 q3 = base2[(size_t)((rowb + cw3) << 6) + lane];

        vf2 S[4], D[4], U[4];
        cstage(q0, S[0], D[0], U[0]);
        cstage(q1, S[1], D[1], U[1]);
        cstage(q2, S[2], D[2], U[2]);
        cstage(q3, S[3], D[3], U[3]);

        int slot = r % 3;
#pragma unroll
        for (int o = 0; o < 2; ++o) {
            vf2 D0 = D[o], D1 = D[o + 1], D2 = D[o + 2];
            vf2 S0 = S[o], S1 = S[o + 1], S2 = S[o + 2];
            vf2 U0 = U[o], U1 = U[o + 1], U2 = U[o + 2];
            vf2 tD = D0 + D2;
            sbD[o][slot] = __builtin_elementwise_fma(two, D1, tD);
            ubD[o][slot] = tD + D1;
            vf2 tS = S0 + S2;
            sbS[o][slot] = __builtin_elementwise_fma(two, S1, tS);
            ubS[o][slot] = tS + S1;
            dbS[o][slot] = S2 - S0;
            vf2 tU = U0 + U2;
            sbU[o][slot] = __builtin_elementwise_fma(two, U1, tU);
            dbU[o][slot] = U2 - U0;
        }

        if (r >= 2) {
            int s0 = (r - 2) % 3, s1 = (r - 1) % 3, s2 = slot;
            int hout = h0 + r - 2;
#pragma unroll
            for (int o = 0; o < 2; ++o) {
                vf2 tsbD = sbD[o][s0] + sbD[o][s2];
                vf2 Gssd = __builtin_elementwise_fma(two, sbD[o][s1], tsbD);
                vf2 Gusd = tsbD + sbD[o][s1];
                vf2 tubD = ubD[o][s0] + ubD[o][s2];
                vf2 Gsud = __builtin_elementwise_fma(two, ubD[o][s1], tubD);
                vf2 tdbS = dbS[o][s0] + dbS[o][s2];
                vf2 Gsds = __builtin_elementwise_fma(two, dbS[o][s1], tdbS);
                vf2 Guds = tdbS + dbS[o][s1];
                vf2 Gdss = sbS[o][s2] - sbS[o][s0];
                vf2 Gdus = ubS[o][s2] - ubS[o][s0];
                vf2 tdbU = dbU[o][s0] + dbU[o][s2];
                vf2 Gsdu = __builtin_elementwise_fma(two, dbU[o][s1], tdbU);
                vf2 Gdsu = sbU[o][s2] - sbU[o][s0];

                vf2 f0 = Gssd;
                vf2 f1 = Gsds;
                vf2 f2 = Gdss;
                vf2 f3 = Gsud - Gsdu;
                vf2 f4 = Gsud + Gsdu;
                vf2 f5 = Gdus - Guds;
                vf2 f6 = Gdus + Guds;
                vf2 f7 = Gusd - Gdsu;
                vf2 f8 = Gusd + Gdsu;

                vf2 s = {9.0f * 1e-6f, 9.0f * 1e-6f};
                vf2 u;
                u = f0 + e1v; s = __builtin_elementwise_fma(u, u, s);
                u = f1 + e1v; s = __builtin_elementwise_fma(u, u, s);
                u = f2 + e1v; s = __builtin_elementwise_fma(u, u, s);
                u = f3 + e1v; s = __builtin_elementwise_fma(u, u, s);
                u = f4 + e1v; s = __builtin_elementwise_fma(u, u, s);
                u = f5 + e1v; s = __builtin_elementwise_fma(u, u, s);
                u = f6 + e1v; s = __builtin_elementwise_fma(u, u, s);
                u = f7 + e1v; s = __builtin_elementwise_fma(u, u, s);
                u = f8 + e1v; s = __builtin_elementwise_fma(u, u, s);

                float2 m2;
                m2.x = sqrtf(s.x);
                m2.y = sqrtf(s.y);

                __half2 hm2 = __float22half2_rn(m2);
                float2 mr = __half22float2(hm2);
                int h2idx = (((b * 128 + hout) * 128 + (w0 + o)) << 6) + lane;
                __builtin_nontemporal_store(*(unsigned int*)&hm2,
                    (unsigned int*)((__half2*)dst + h2idx));
                mn = fminf(mn, fminf(mr.x, mr.y));
                mx = fmaxf(mx, fmaxf(mr.x, mr.y));
            }
        }
    }

    // Block min/max reduce (uint trick valid: m > 0), plain store to unique slot
    unsigned int umn = __float_as_uint(mn);
    unsigned int umx = __float_as_uint(mx);
#pragma unroll
    for (int off = 32; off > 0; off >>= 1) {
        unsigned int a1 = __shfl_down(umn, off, 64);
        unsigned int b1 = __shfl_down(umx, off, 64);
        umn = (a1 < umn) ? a1 : umn;
        umx = (b1 > umx) ? b1 : umx;
    }
    __shared__ unsigned int smn[4], smx[4];
    if (lane == 0) { smn[wid] = umn; smx[wid] = umx; }
    __syncthreads();
    if (tid == 0) {
        unsigned int m0 = smn[0] < smn[1] ? smn[0] : smn[1];
        unsigned int m1 = smn[2] < smn[3] ? smn[2] : smn[3];
        unsigned int x0 = smx[0] > smx[1] ? smx[0] : smx[1];
        unsigned int x1 = smx[2] > smx[3] ? smx[2] : smx[3];
        g_bmin[bid] = (m0 < m1 ? m0 : m1);
        g_bmax[bid] = (x0 > x1 ? x0 : x1);
    }
}

// ---------------------------------------------------------------------------
// Pass 2 (R10-proven, slots = 1024): every block redundantly reduces the 8 KB
// of min/max slots (LLC-resident; no fences), streams its sequential shard of
// both fp16 mag arrays, one pre-scaled atomicAdd(out).
// ---------------------------------------------------------------------------
__global__ __launch_bounds__(TPB) void pass2_kernel(
    const uint4* __restrict__ magx8, const uint4* __restrict__ magy8,
    float* __restrict__ out) {
    int tid = threadIdx.x, bid = blockIdx.x;
    int lane = tid & 63, wid = tid >> 6;
    __shared__ unsigned int sred[4][4];
    __shared__ float smm[4];
    __shared__ float sv[4];

    // ---- redundant global min/max reduce: 512 slots per image = 128 uint4 ----
    const uint4* bmin4 = (const uint4*)g_bmin;   // [0,128): img x, [128,256): img y
    const uint4* bmax4 = (const uint4*)g_bmax;
    unsigned int v0 = 0xFFFFFFFFu, v1 = 0u, v2 = 0xFFFFFFFFu, v3 = 0u;
    if (tid < 128) {
        uint4 a = bmin4[tid];
        uint4 b = bmax4[tid];
        uint4 c = bmin4[tid + 128];
        uint4 d = bmax4[tid + 128];
        unsigned int a01 = (a.x < a.y) ? a.x : a.y, a23 = (a.z < a.w) ? a.z : a.w;
        unsigned int b01 = (b.x > b.y) ? b.x : b.y, b23 = (b.z > b.w) ? b.z : b.w;
        unsigned int c01 = (c.x < c.y) ? c.x : c.y, c23 = (c.z < c.w) ? c.z : c.w;
        unsigned int d01 = (d.x > d.y) ? d.x : d.y, d23 = (d.z > d.w) ? d.z : d.w;
        v0 = (a01 < a23) ? a01 : a23;
        v1 = (b01 > b23) ? b01 : b23;
        v2 = (c01 < c23) ? c01 : c23;
        v3 = (d01 > d23) ? d01 : d23;
    }
#pragma unroll
    for (int off = 32; off > 0; off >>= 1) {
        unsigned int t0 = __shfl_down(v0, off, 64);
        unsigned int t1 = __shfl_down(v1, off, 64);
        unsigned int t2 = __shfl_down(v2, off, 64);
        unsigned int t3 = __shfl_down(v3, off, 64);
        v0 = (t0 < v0) ? t0 : v0;
        v1 = (t1 > v1) ? t1 : v1;
        v2 = (t2 < v2) ? t2 : v2;
        v3 = (t3 > v3) ? t3 : v3;
    }
    if (lane == 0) { sred[wid][0] = v0; sred[wid][1] = v1; sred[wid][2] = v2; sred[wid][3] = v3; }
    __syncthreads();
    if (tid == 0) {
        unsigned int r0 = sred[0][0], r1 = sred[0][1], r2 = sred[0][2], r3 = sred[0][3];
#pragma unroll
        for (int w = 1; w < 4; ++w) {
            r0 = (sred[w][0] < r0) ? sred[w][0] : r0;
            r1 = (sred[w][1] > r1) ? sred[w][1] : r1;
            r2 = (sred[w][2] < r2) ? sred[w][2] : r2;
            r3 = (sred[w][3] > r3) ? sred[w][3] : r3;
        }
        smm[0] = __uint_as_float(r0);
        smm[1] = __uint_as_float(r1);
        smm[2] = __uint_as_float(r2);
        smm[3] = __uint_as_float(r3);
    }
    __syncthreads();

    // ---- normalize + L1 partial sum over this block's sequential shard ----
    float mnx = smm[0], mxx = smm[1], mny = smm[2], mxy = smm[3];
    float ix = 1.0f / (mxx - mnx + 1e-6f);
    float iy = 1.0f / (mxy - mny + 1e-6f);
    float cx = -mnx * ix;
    float cy = -mny * iy;

    float s = 0.0f;
    // NVOX/8 = 1,048,576 uint4 per array; per block 2048 sequential uint4
#pragma unroll
    for (int k = 0; k < 8; ++k) {
        int i = bid * 2048 + k * TPB + tid;
        U4H8 qa, qb;
        qa.u = magx8[i];
        qb.u = magy8[i];
#pragma unroll
        for (int j = 0; j < 4; ++j) {
            float2 va = __half22float2(qa.h[j]);
            float2 vb = __half22float2(qb.h[j]);
            s += fabsf(fmaf(va.x, ix, cx) - fmaf(vb.x, iy, cy));
            s += fabsf(fmaf(va.y, ix, cx) - fmaf(vb.y, iy, cy));
        }
    }
#pragma unroll
    for (int off = 32; off > 0; off >>= 1) s += __shfl_down(s, off, 64);
    if (lane == 0) sv[wid] = s;
    __syncthreads();
    if (tid == 0) {
        float partial = ((sv[0] + sv[1]) + (sv[2] + sv[3])) * (1.0f / (float)NVOX); // *2^-23 exact
        if (bid == 0) partial += 1e-6f;
        atomicAdd(out, partial);
    }
}

extern "C" void kernel_launch(void* const* d_in, const int* in_sizes, int n_in,
                              void* d_out, int out_size, void* d_ws, size_t ws_size,
                              hipStream_t stream) {
    const float* x = (const float*)d_in[0];
    const float* y = (const float*)d_in[1];
    // d_in[2] = kernels (weights hardcoded via separable factorization)
    float* out = (float*)d_out;

    __half* magx = (__half*)d_ws;            // NVOX halfs (16 MiB)
    __half* magy = magx + NVOX;              // NVOX halfs (16 MiB)

    pass1_kernel<<<NBLK1, 256, 0, stream>>>(x, y, magx, magy, out);
    pass2_kernel<<<GRID2, TPB, 0, stream>>>((const uint4*)magx, (const uint4*)magy, out);
}